// Round 7
// baseline (425.335 us; speedup 1.0000x reference)
//
#include <hip/hip_runtime.h>

#define BATCH 1024
#define NNODE 92
#define FIN   1024
#define FOUT  512

typedef float    f32x4 __attribute__((ext_vector_type(4)));
typedef _Float16 half8 __attribute__((ext_vector_type(8)));
typedef _Float16 half4 __attribute__((ext_vector_type(4)));

__device__ __forceinline__ float lrelu(float x) { return fmaxf(x, 0.2f * x); }

#define BAR_LGKM() do {                                                        \
    asm volatile("s_waitcnt lgkmcnt(0)" ::: "memory");                         \
    __builtin_amdgcn_sched_barrier(0);                                         \
    __builtin_amdgcn_s_barrier();                                              \
  } while (0)

// ---------------------------------------------------------------------------
// prep: WT[n][k] = f16(W[k][n]);  ATp[j][k] = f16(A[k][j]) padded [96][104]
// ---------------------------------------------------------------------------
__global__ __launch_bounds__(256) void prep_kernel(
    const float* __restrict__ W, const float* __restrict__ Am,
    _Float16* __restrict__ WT, _Float16* __restrict__ ATp) {
  int bid = blockIdx.x, t = threadIdx.x;
  if (bid < 64) {
    int n0 = bid * 8;
    for (int it = 0; it < 4; ++it) {
      int k = it * 256 + t;
      const f32x4* src = (const f32x4*)(W + (size_t)k * FOUT + n0);
      f32x4 v0 = src[0], v1 = src[1];
      #pragma unroll
      for (int c = 0; c < 4; ++c) {
        WT[(size_t)(n0 + c) * FIN + k]     = (_Float16)v0[c];
        WT[(size_t)(n0 + 4 + c) * FIN + k] = (_Float16)v1[c];
      }
    }
  } else {
    int j0 = (bid - 64) * 24;
    for (int idx = t; idx < 24 * 104; idx += 256) {
      int jr = idx / 104, k = idx - jr * 104;
      int j = j0 + jr;
      float v = (j < NNODE && k < NNODE) ? Am[k * NNODE + j] : 0.f;
      ATp[j * 104 + k] = (_Float16)v;
    }
  }
}

// ---------------------------------------------------------------------------
// K1: Wh = X @ W. 736 blocks x 1024 thr, tile 128m x 512n (full N), BK=32.
//     B-fragments load DIRECTLY global->regs (no LDS round-trip, no glds),
//     double-buffered one phase ahead; only the A tile goes through LDS
//     (16 KB/phase, swizzled). Raw lgkmcnt(0)+s_barrier per phase; vmcnt
//     left to the compiler. Epilogue: fused Wh1/Wh2 reduction (red[m][16]:
//     one writer per (m, wc) -- fixed from R6's uninitialized-slot bug) +
//     LDS transpose -> coalesced Wh[b][f][96] stores.
// ---------------------------------------------------------------------------
__global__ __launch_bounds__(1024, 4) void gemm_kernel(
    const float* __restrict__ X, const _Float16* __restrict__ WT,
    const float* __restrict__ av, _Float16* __restrict__ Wh,
    float* __restrict__ Wh1g, float* __restrict__ Wh2g) {
  extern __shared__ char smem[];
  _Float16* Al0 = (_Float16*)smem;             // [128][32] f16 swz, 8192 B
  _Float16* Al1 = (_Float16*)(smem + 8192);
  _Float16* tbuf = (_Float16*)smem;            // [128][513] f16 epilogue
  float* red = (float*)smem;                   // [128][16] f32 (after loop)

  int t = threadIdx.x;
  int l = t & 63, w = t >> 6;
  int wm = w >> 3, wc = w & 7;                 // wave grid 2m x 8n, 64x64 each
  unsigned m0 = (unsigned)blockIdx.x * 128u;

  // A path: thread loads X[row=t>>3][(t&7)*4 ..+3], writes slot-swizzled LDS
  int arow = t >> 3, k8 = t & 7;
  const float* Xbase = X + ((size_t)m0 + arow) * FIN + k8 * 4;
  int awoff = arow * 64 + (((k8 >> 1) ^ ((arow >> 1) & 3)) << 4) + (k8 & 1) * 8;

  // B direct-from-global fragment base: lane n = wc*64+ni*16+(l&15),
  // k-run = kt*32 + (l>>4)*8 (+8 f16 = 16B contiguous)
  const _Float16* WTb = WT + (size_t)(wc * 64 + (l & 15)) * FIN + (l >> 4) * 8;

  // A fragment read offsets (swizzle key = (row>>1)&3 = (l>>1)&3)
  int fsw = (((l >> 4) ^ ((l >> 1) & 3)) << 4);
  int aoff[4];
  #pragma unroll
  for (int mi = 0; mi < 4; ++mi)
    aoff[mi] = (wm * 64 + mi * 16 + (l & 15)) * 64 + fsw;

  f32x4 zz = {0.f, 0.f, 0.f, 0.f};
  f32x4 acc[4][4];
  #pragma unroll
  for (int mi = 0; mi < 4; ++mi)
    #pragma unroll
    for (int ni = 0; ni < 4; ++ni) acc[mi][ni] = zz;

  f32x4 xvA, xvB;
  half8 bfA[4], bfB[4];

#define K1_XLOAD(XV, KT) (XV) = *(const f32x4*)(Xbase + (size_t)(KT) * 32)

#define K1_BFLOAD(DST, KT) do {                                                \
    _Pragma("unroll")                                                          \
    for (int ni = 0; ni < 4; ++ni)                                             \
      (DST)[ni] = *(const half8*)(WTb + (size_t)(ni * 16) * FIN + (KT) * 32);  \
  } while (0)

#define K1_AWRITE(NA, XV) do {                                                 \
    half4 h;                                                                   \
    h[0] = (_Float16)(XV)[0]; h[1] = (_Float16)(XV)[1];                        \
    h[2] = (_Float16)(XV)[2]; h[3] = (_Float16)(XV)[3];                        \
    *(half4*)((char*)(NA) + awoff) = h;                                        \
  } while (0)

#define K1_MFMA(CA, BF) do {                                                   \
    half8 af[4];                                                               \
    _Pragma("unroll")                                                          \
    for (int mi = 0; mi < 4; ++mi)                                             \
      af[mi] = *(const half8*)((const char*)(CA) + aoff[mi]);                  \
    _Pragma("unroll")                                                          \
    for (int mi = 0; mi < 4; ++mi)                                             \
      _Pragma("unroll")                                                        \
      for (int ni = 0; ni < 4; ++ni)                                           \
        acc[mi][ni] = __builtin_amdgcn_mfma_f32_16x16x32_f16(                  \
            af[mi], (BF)[ni], acc[mi][ni], 0, 0, 0);                           \
  } while (0)

  // prologue: A(0) staged, X(1) + B(0) in flight
  K1_XLOAD(xvA, 0);
  K1_XLOAD(xvB, 1);
  K1_BFLOAD(bfA, 0);
  K1_AWRITE(Al0, xvA);            // compiler waits vmcnt for xvA
  BAR_LGKM();

  #pragma unroll 1
  for (int kt = 0; kt < 32; kt += 2) {
    // even phase: compute tile kt (Al0, bfA)
    if (kt + 2 < 32) K1_XLOAD(xvA, kt + 2);
    K1_BFLOAD(bfB, kt + 1);
    K1_MFMA(Al0, bfA);
    K1_AWRITE(Al1, xvB);          // xvB = X(kt+1)
    BAR_LGKM();
    // odd phase: compute tile kt+1 (Al1, bfB)
    if (kt + 3 < 32) K1_XLOAD(xvB, kt + 3);
    if (kt + 2 < 32) K1_BFLOAD(bfA, kt + 2);
    K1_MFMA(Al1, bfB);
    if (kt + 2 < 32) K1_AWRITE(Al0, xvA);
    BAR_LGKM();
  }

  // ---- fused Wh1/Wh2 = acc . a
  // red layout [m][16]: 8 n-groups (wc) x {s1,s2}. For each m exactly the
  // waves with wm == m>>6 write, one slot per wc -> every slot initialized.
  float aC1[4], aC2[4];
  #pragma unroll
  for (int ni = 0; ni < 4; ++ni) {
    int C = wc * 64 + ni * 16 + (l & 15);
    aC1[ni] = av[C];
    aC2[ni] = av[FOUT + C];
  }
  float p1[4][4], p2[4][4];
  #pragma unroll
  for (int mi = 0; mi < 4; ++mi)
    #pragma unroll
    for (int r = 0; r < 4; ++r) {
      float s1 = 0.f, s2 = 0.f;
      #pragma unroll
      for (int ni = 0; ni < 4; ++ni) {
        s1 = fmaf(acc[mi][ni][r], aC1[ni], s1);
        s2 = fmaf(acc[mi][ni][r], aC2[ni], s2);
      }
      p1[mi][r] = s1; p2[mi][r] = s2;
    }
  #pragma unroll
  for (int mm = 1; mm < 16; mm <<= 1)
    #pragma unroll
    for (int mi = 0; mi < 4; ++mi)
      #pragma unroll
      for (int r = 0; r < 4; ++r) {
        p1[mi][r] += __shfl_xor(p1[mi][r], mm);
        p2[mi][r] += __shfl_xor(p2[mi][r], mm);
      }
  if ((l & 15) == 0) {
    #pragma unroll
    for (int mi = 0; mi < 4; ++mi)
      #pragma unroll
      for (int r = 0; r < 4; ++r) {
        int m = wm * 64 + mi * 16 + (l >> 4) * 4 + r;
        red[m * 16 + wc * 2]     = p1[mi][r];
        red[m * 16 + wc * 2 + 1] = p2[mi][r];
      }
  }
  __syncthreads();
  if (t < 128) {
    float s1 = 0.f, s2 = 0.f;
    #pragma unroll
    for (int q = 0; q < 8; ++q) {
      s1 += red[t * 16 + q * 2];
      s2 += red[t * 16 + q * 2 + 1];
    }
    Wh1g[m0 + t] = s1;
    Wh2g[m0 + t] = s2;
  }
  __syncthreads();

  // ---- dump acc -> tbuf m-major [128][513]
  #pragma unroll
  for (int mi = 0; mi < 4; ++mi)
    #pragma unroll
    for (int ni = 0; ni < 4; ++ni) {
      int C = wc * 64 + ni * 16 + (l & 15);
      #pragma unroll
      for (int r = 0; r < 4; ++r) {
        int m = wm * 64 + mi * 16 + (l >> 4) * 4 + r;
        tbuf[m * 513 + C] = (_Float16)acc[mi][ni][r];
      }
    }
  __syncthreads();

  // ---- coalesced stores: thread t (<512) owns column C=t of Wh[b][f][96]
  if (t < 512) {
    unsigned mEnd = m0 + 128u;
    unsigned b0 = m0 / 92u;
    #pragma unroll 1
    for (unsigned seg = 0; seg < 3; ++seg) {
      unsigned bbase = b0 + seg;
      unsigned bstart = bbase * 92u;
      if (bstart >= mEnd) break;
      unsigned s = (bstart < m0) ? (m0 - bstart) : 0u;
      unsigned e = (mEnd - bstart < 92u) ? (mEnd - bstart) : 92u;
      if (s >= e) continue;
      _Float16* gp = Wh + ((size_t)bbase * FOUT + t) * 96;
      for (unsigned m8 = s & ~7u; m8 < e; m8 += 8) {
        unsigned lo = (m8 < s) ? s : m8;
        unsigned hi = (m8 + 8 > e) ? e : m8 + 8;
        if (hi - lo == 8) {
          half8 v;
          #pragma unroll
          for (int q = 0; q < 8; ++q)
            v[q] = tbuf[(bstart + lo - m0 + q) * 513 + t];
          *(half8*)(gp + lo) = v;
        } else {
          for (unsigned m = lo; m < hi; ++m)
            gp[m] = tbuf[(bstart + m - m0) * 513 + t];
        }
      }
    }
  }
}

// ---------------------------------------------------------------------------
// K2: per-batch attention. QK+softmax from LDS (at_, e0a); PV over 8 chunks
//     of 64 f-rows, reg-staged (3 rotating sets, 2 chunks in flight under
//     QK), double-buffered LDS [64][104], one raw barrier per chunk.
// ---------------------------------------------------------------------------
__global__ __launch_bounds__(512, 4) void attn_kernel(
    const _Float16* __restrict__ Wh, const _Float16* __restrict__ ATp,
    const int* __restrict__ adj, const float* __restrict__ Wh1g,
    const float* __restrict__ Wh2g, const float* __restrict__ bias,
    float* __restrict__ out) {
  extern __shared__ char smem[];
  _Float16* at_  = (_Float16*)smem;                 // [96][104] 19968 B
  _Float16* e0a  = (_Float16*)(smem + 19968);       // [96][104] 19968 B
  _Float16* whc0 = (_Float16*)(smem + 39936);       // [64][104] 13312 B
  _Float16* whc1 = (_Float16*)(smem + 53248);       // [64][104] 13312 B
  float* w1s = (float*)(smem + 66560);              // [96]
  float* w2s = (float*)(smem + 66944);              // [96]

  int t = threadIdx.x, l = t & 63, w = t >> 6;
  int b = blockIdx.x;
  const _Float16* WhB = Wh + (size_t)b * FOUT * 96;

  // chunk staging: threads 0..383, 16 f16 each (one whc row = 6 threads)
  half8 st[3][2];
  bool stager = (t < 384);
  int srow = t / 6, scol = (t - srow * 6) * 16;

#define K2_LD(S, C) do { if (stager) {                                         \
    st[S][0] = *(const half8*)(WhB + (C) * 6144 + t * 16);                     \
    st[S][1] = *(const half8*)(WhB + (C) * 6144 + t * 16 + 8); } } while (0)
#define K2_WR(BUF, S) do { if (stager) {                                       \
    *(half8*)((BUF) + srow * 104 + scol)     = st[S][0];                       \
    *(half8*)((BUF) + srow * 104 + scol + 8) = st[S][1]; } } while (0)

  K2_LD(0, 0);
  K2_LD(1, 1);

  for (int idx = t; idx < 1248; idx += 512)
    *(half8*)(at_ + idx * 8) = *(const half8*)(ATp + idx * 8);
  if (t < 96) w1s[t] = (t < 92) ? Wh1g[(size_t)b * NNODE + t] : 0.f;
  else if (t < 192) {
    int j = t - 96;
    w2s[j] = (j < 92) ? Wh2g[(size_t)b * NNODE + j] : 0.f;
  }
  BAR_LGKM();

  // e0[i][k] = lrelu(Wh1[i]+Wh2[k]), zero-padded to [96][104]
  for (int idx = t; idx < 96 * 128; idx += 512) {
    int i = idx >> 7, k = idx & 127;
    if (k < 104) {
      float v = (i < 92 && k < 92) ? lrelu(w1s[i] + w2s[k]) : 0.f;
      e0a[i * 104 + k] = (_Float16)v;
    }
  }
  BAR_LGKM();

  if (w < 6) {
    f32x4 ez = {0.f, 0.f, 0.f, 0.f};
    f32x4 eacc[6];
    #pragma unroll
    for (int ni = 0; ni < 6; ++ni) eacc[ni] = ez;
    #pragma unroll
    for (int ks = 0; ks < 3; ++ks) {
      half8 ea = *(const half8*)((const char*)e0a +
                 (16 * w + (l & 15)) * 208 + ks * 64 + (l >> 4) * 16);
      #pragma unroll
      for (int ni = 0; ni < 6; ++ni) {
        half8 bt = *(const half8*)((const char*)at_ +
                   (16 * ni + (l & 15)) * 208 + ks * 64 + (l >> 4) * 16);
        eacc[ni] = __builtin_amdgcn_mfma_f32_16x16x32_f16(ea, bt, eacc[ni], 0, 0, 0);
      }
    }
    float attv[4][6];
    #pragma unroll
    for (int r = 0; r < 4; ++r) {
      int i = 16 * w + (l >> 4) * 4 + r;
      float s[6]; float m = -3.0e38f;
      #pragma unroll
      for (int ni = 0; ni < 6; ++ni) {
        int j = ni * 16 + (l & 15);
        float e = lrelu(eacc[ni][r]);
        float sv = -3.0e38f;
        if (i < 92 && j < 92) {
          int avj = adj[((size_t)b * NNODE + i) * NNODE + j];
          sv = (avj > 0) ? e : -9.0e15f;
        }
        s[ni] = sv;
        m = fmaxf(m, sv);
      }
      #pragma unroll
      for (int mm = 1; mm < 16; mm <<= 1) m = fmaxf(m, __shfl_xor(m, mm));
      float sum = 0.f; float p[6];
      #pragma unroll
      for (int ni = 0; ni < 6; ++ni) {
        int j = ni * 16 + (l & 15);
        p[ni] = (i < 92 && j < 92) ? __expf(s[ni] - m) : 0.f;
        sum += p[ni];
      }
      #pragma unroll
      for (int mm = 1; mm < 16; mm <<= 1) sum += __shfl_xor(sum, mm);
      float rs = (i < 92) ? (1.0f / sum) : 0.f;
      #pragma unroll
      for (int ni = 0; ni < 6; ++ni) attv[r][ni] = p[ni] * rs;
    }
    // att back into e0a (each wave touches only its own rows)
    #pragma unroll
    for (int r = 0; r < 4; ++r) {
      int i = 16 * w + (l >> 4) * 4 + r;
      #pragma unroll
      for (int ni = 0; ni < 6; ++ni)
        e0a[i * 104 + ni * 16 + (l & 15)] = (_Float16)attv[r][ni];
    }
  }
  BAR_LGKM();          // att visible to all waves

  K2_WR(whc0, 0);      // compiler waits vmcnt for set0 only
  BAR_LGKM();          // chunk 0 ready

  // PV: wave (ih = w>>2, fq = w&3): rows mi = ih*3+q, f-col fq*16+(l&15)
  int ih = w >> 2, fq = w & 3;
  #pragma unroll
  for (int c = 0; c < 8; ++c) {
    _Float16* cur = (c & 1) ? whc1 : whc0;
    _Float16* nxt = (c & 1) ? whc0 : whc1;
    if (c + 1 < 8) K2_WR(nxt, (c + 1) % 3);
    if (c + 2 < 8) K2_LD((c + 2) % 3, c + 2);
    f32x4 pz = {0.f, 0.f, 0.f, 0.f};
    f32x4 pacc[3];
    pacc[0] = pz; pacc[1] = pz; pacc[2] = pz;
    #pragma unroll
    for (int ks = 0; ks < 3; ++ks) {
      half8 bf = *(const half8*)((const char*)cur +
                 (fq * 16 + (l & 15)) * 208 + ks * 64 + (l >> 4) * 16);
      #pragma unroll
      for (int q = 0; q < 3; ++q) {
        half8 af = *(const half8*)((const char*)e0a +
                   (16 * (ih * 3 + q) + (l & 15)) * 208 + ks * 64 + (l >> 4) * 16);
        pacc[q] = __builtin_amdgcn_mfma_f32_16x16x32_f16(af, bf, pacc[q], 0, 0, 0);
      }
    }
    int fcol = c * 64 + fq * 16 + (l & 15);
    float bv = bias[fcol];
    #pragma unroll
    for (int q = 0; q < 3; ++q)
      #pragma unroll
      for (int r = 0; r < 4; ++r) {
        int i = 16 * (ih * 3 + q) + (l >> 4) * 4 + r;
        if (i < 92)
          out[((size_t)b * NNODE + i) * FOUT + fcol] = pacc[q][r] + bv;
      }
    if (c + 1 < 8) BAR_LGKM();
  }
}

// ---------------------------------------------------------------------------
extern "C" void kernel_launch(void* const* d_in, const int* in_sizes, int n_in,
                              void* d_out, int out_size, void* d_ws, size_t ws_size,
                              hipStream_t stream) {
  (void)in_sizes; (void)n_in; (void)out_size; (void)ws_size;
  const float* X    = (const float*)d_in[0];
  const int*   adj  = (const int*)d_in[1];
  const float* W    = (const float*)d_in[2];
  const float* av   = (const float*)d_in[3];
  const float* Am   = (const float*)d_in[4];
  const float* bias = (const float*)d_in[5];
  float* out = (float*)d_out;
  char* ws = (char*)d_ws;

  _Float16* WT  = (_Float16*)(ws);              // 1,048,576 B
  _Float16* ATp = (_Float16*)(ws + 1048576);    //    19,968 B
  float* Wh1 = (float*)(ws + 1068544);          //   376,832 B
  float* Wh2 = (float*)(ws + 1445376);          //   376,832 B
  _Float16* Wh = (_Float16*)(ws + 1822208);     // 100,663,296 B  [b][f][96]

  prep_kernel<<<68, 256, 0, stream>>>(W, Am, WT, ATp);
  hipFuncSetAttribute((const void*)gemm_kernel,
                      hipFuncAttributeMaxDynamicSharedMemorySize, 131328);
  gemm_kernel<<<736, 1024, 131328, stream>>>(X, WT, av, Wh, Wh1, Wh2);
  hipFuncSetAttribute((const void*)attn_kernel,
                      hipFuncAttributeMaxDynamicSharedMemorySize, 67584);
  attn_kernel<<<1024, 512, 67584, stream>>>(Wh, ATp, adj, Wh1, Wh2, bias, out);
}

// Round 8
// 370.945 us; speedup vs baseline: 1.1466x; 1.1466x over previous
//
#include <hip/hip_runtime.h>

#define BATCH 1024
#define NNODE 92
#define FIN   1024
#define FOUT  512

typedef float    f32x4 __attribute__((ext_vector_type(4)));
typedef _Float16 half8 __attribute__((ext_vector_type(8)));
typedef _Float16 half4 __attribute__((ext_vector_type(4)));

__device__ __forceinline__ float lrelu(float x) { return fmaxf(x, 0.2f * x); }

#define BAR_LGKM() do {                                                        \
    asm volatile("s_waitcnt lgkmcnt(0)" ::: "memory");                         \
    __builtin_amdgcn_sched_barrier(0);                                         \
    __builtin_amdgcn_s_barrier();                                              \
  } while (0)

// ---------------------------------------------------------------------------
// prep: WT[n][k] = f16(W[k][n]);  ATp[j][k] = f16(A[k][j]) padded [96][104]
// ---------------------------------------------------------------------------
__global__ __launch_bounds__(256) void prep_kernel(
    const float* __restrict__ W, const float* __restrict__ Am,
    _Float16* __restrict__ WT, _Float16* __restrict__ ATp) {
  int bid = blockIdx.x, t = threadIdx.x;
  if (bid < 64) {
    int n0 = bid * 8;
    for (int it = 0; it < 4; ++it) {
      int k = it * 256 + t;
      const f32x4* src = (const f32x4*)(W + (size_t)k * FOUT + n0);
      f32x4 v0 = src[0], v1 = src[1];
      #pragma unroll
      for (int c = 0; c < 4; ++c) {
        WT[(size_t)(n0 + c) * FIN + k]     = (_Float16)v0[c];
        WT[(size_t)(n0 + 4 + c) * FIN + k] = (_Float16)v1[c];
      }
    }
  } else {
    int j0 = (bid - 64) * 24;
    for (int idx = t; idx < 24 * 104; idx += 256) {
      int jr = idx / 104, k = idx - jr * 104;
      int j = j0 + jr;
      float v = (j < NNODE && k < NNODE) ? Am[k * NNODE + j] : 0.f;
      ATp[j * 104 + k] = (_Float16)v;
    }
  }
}

// ---------------------------------------------------------------------------
// K1: Wh = X @ W. 2944 blocks x 512 thr: m-tile = bid>>1 (64 rows),
//     n-half = bid&1 (256 cols). 8 waves as 2m x 4n, wave 32m x 64n,
//     acc 32 f32/lane. BK=32, glds B dbuf, A-LDS dbuf, counted vmcnt(1)
//     per phase, clamped tail loads (uniform phases). Epilogue: direct
//     half4 stores (92%4==0: m-quads never straddle batches); Wh1/Wh2
//     per-half partials into Wh1h + nh*94208.
// ---------------------------------------------------------------------------
__global__ __launch_bounds__(512, 4) void gemm_kernel(
    const float* __restrict__ X, const _Float16* __restrict__ WT,
    const float* __restrict__ av, _Float16* __restrict__ Wh,
    float* __restrict__ Wh1h, float* __restrict__ Wh2h) {
  extern __shared__ char smem[];
  _Float16* Al0 = (_Float16*)smem;             // [64][32] f16 swz, 4096 B
  _Float16* Al1 = (_Float16*)(smem + 4096);
  _Float16* Bl0 = (_Float16*)(smem + 8192);    // [256][32] f16 swz, 16384 B
  _Float16* Bl1 = (_Float16*)(smem + 24576);
  float* red = (float*)(smem + 40960);         // [64][8] f32, 2048 B

  int t = threadIdx.x;
  int l = t & 63, w = t >> 6;
  int wm = w >> 2, wc = w & 3;                 // wave grid 2m x 4n
  unsigned bid = blockIdx.x;
  unsigned mt = bid >> 1, nh = bid & 1;
  unsigned m0 = mt * 64u;
  int n0 = (int)nh * 256;

  int arow = t >> 3, k8 = t & 7;
  const float* Xbase = X + ((size_t)m0 + arow) * FIN + k8 * 4;
  int awoff = arow * 64 + (((k8 >> 1) ^ ((arow >> 1) & 3)) << 4) + (k8 & 1) * 8;

  int brow = w * 16 + (l >> 2);
  int bsrc = ((l & 3) ^ ((l >> 3) & 3)) * 8;   // f16 units

  int fsw = (((l >> 4) ^ ((l >> 1) & 3)) << 4);
  int aoff[2], boff[4];
  #pragma unroll
  for (int mi = 0; mi < 2; ++mi)
    aoff[mi] = (wm * 32 + mi * 16 + (l & 15)) * 64 + fsw;
  #pragma unroll
  for (int ni = 0; ni < 4; ++ni)
    boff[ni] = (wc * 64 + ni * 16 + (l & 15)) * 64 + fsw;

  float aC1[4], aC2[4];
  #pragma unroll
  for (int ni = 0; ni < 4; ++ni) {
    int C = n0 + wc * 64 + ni * 16 + (l & 15);
    aC1[ni] = av[C];
    aC2[ni] = av[FOUT + C];
  }

  f32x4 zz = {0.f, 0.f, 0.f, 0.f};
  f32x4 acc[2][4];
  #pragma unroll
  for (int mi = 0; mi < 2; ++mi)
    #pragma unroll
    for (int ni = 0; ni < 4; ++ni) acc[mi][ni] = zz;

  f32x4 xvA, xvB;

#define K1_XLOAD(XV, KT) do {                                                  \
    int ktc_ = (KT) > 31 ? 31 : (KT);                                          \
    (XV) = *(const f32x4*)(Xbase + (size_t)ktc_ * 32);                         \
  } while (0)

#define K1_GLDS(NB, KT) do {                                                   \
    int ktc_ = (KT) > 31 ? 31 : (KT);                                          \
    _Pragma("unroll")                                                          \
    for (int p = 0; p < 2; ++p) {                                              \
      const _Float16* gp = WT + (size_t)(n0 + p * 128 + brow) * FIN +          \
                           ktc_ * 32 + bsrc;                                   \
      char* lp = (char*)(NB) + p * 8192 + w * 1024;                            \
      __builtin_amdgcn_global_load_lds(                                        \
          (const __attribute__((address_space(1))) void*)gp,                   \
          (__attribute__((address_space(3))) void*)lp, 16, 0, 0);              \
    }                                                                          \
  } while (0)

#define K1_AWRITE(NA, XV) do {                                                 \
    half4 h;                                                                   \
    h[0] = (_Float16)(XV)[0]; h[1] = (_Float16)(XV)[1];                        \
    h[2] = (_Float16)(XV)[2]; h[3] = (_Float16)(XV)[3];                        \
    *(half4*)((char*)(NA) + awoff) = h;                                        \
  } while (0)

#define K1_MFMA(CA, CB) do {                                                   \
    half8 af[2], bf[4];                                                        \
    _Pragma("unroll")                                                          \
    for (int mi = 0; mi < 2; ++mi)                                             \
      af[mi] = *(const half8*)((const char*)(CA) + aoff[mi]);                  \
    _Pragma("unroll")                                                          \
    for (int ni = 0; ni < 4; ++ni)                                             \
      bf[ni] = *(const half8*)((const char*)(CB) + boff[ni]);                  \
    _Pragma("unroll")                                                          \
    for (int mi = 0; mi < 2; ++mi)                                             \
      _Pragma("unroll")                                                        \
      for (int ni = 0; ni < 4; ++ni)                                           \
        acc[mi][ni] = __builtin_amdgcn_mfma_f32_16x16x32_f16(                  \
            af[mi], bf[ni], acc[mi][ni], 0, 0, 0);                             \
  } while (0)

  // prologue
  K1_XLOAD(xvA, 0);
  K1_XLOAD(xvB, 1);
  K1_GLDS(Bl0, 0);
  K1_AWRITE(Al0, xvA);
  asm volatile("s_waitcnt vmcnt(0) lgkmcnt(0)" ::: "memory");
  __builtin_amdgcn_sched_barrier(0);
  __builtin_amdgcn_s_barrier();

  #pragma unroll 1
  for (int kt = 0; kt < 32; kt += 2) {
    K1_GLDS(Bl1, kt + 1);
    K1_XLOAD(xvA, kt + 2);
    K1_MFMA(Al0, Bl0);
    K1_AWRITE(Al1, xvB);
    asm volatile("s_waitcnt vmcnt(1)" ::: "memory");
    asm volatile("s_waitcnt lgkmcnt(0)" ::: "memory");
    __builtin_amdgcn_sched_barrier(0);
    __builtin_amdgcn_s_barrier();
    K1_GLDS(Bl0, kt + 2);
    K1_XLOAD(xvB, kt + 3);
    K1_MFMA(Al1, Bl1);
    K1_AWRITE(Al0, xvA);
    asm volatile("s_waitcnt vmcnt(1)" ::: "memory");
    asm volatile("s_waitcnt lgkmcnt(0)" ::: "memory");
    __builtin_amdgcn_sched_barrier(0);
    __builtin_amdgcn_s_barrier();
  }

  // ---- Wh1/Wh2 partials for this n-half
  float p1[2][4], p2[2][4];
  #pragma unroll
  for (int mi = 0; mi < 2; ++mi)
    #pragma unroll
    for (int r = 0; r < 4; ++r) {
      float s1 = 0.f, s2 = 0.f;
      #pragma unroll
      for (int ni = 0; ni < 4; ++ni) {
        s1 = fmaf(acc[mi][ni][r], aC1[ni], s1);
        s2 = fmaf(acc[mi][ni][r], aC2[ni], s2);
      }
      p1[mi][r] = s1; p2[mi][r] = s2;
    }
  #pragma unroll
  for (int mm = 1; mm < 16; mm <<= 1)
    #pragma unroll
    for (int mi = 0; mi < 2; ++mi)
      #pragma unroll
      for (int r = 0; r < 4; ++r) {
        p1[mi][r] += __shfl_xor(p1[mi][r], mm);
        p2[mi][r] += __shfl_xor(p2[mi][r], mm);
      }
  if ((l & 15) == 0) {
    #pragma unroll
    for (int mi = 0; mi < 2; ++mi)
      #pragma unroll
      for (int r = 0; r < 4; ++r) {
        int m = wm * 32 + mi * 16 + (l >> 4) * 4 + r;
        red[m * 8 + wc * 2]     = p1[mi][r];
        red[m * 8 + wc * 2 + 1] = p2[mi][r];
      }
  }
  __syncthreads();
  if (t < 64) {
    float s1 = 0.f, s2 = 0.f;
    #pragma unroll
    for (int q = 0; q < 4; ++q) {
      s1 += red[t * 8 + q * 2];
      s2 += red[t * 8 + q * 2 + 1];
    }
    size_t off = (size_t)nh * 94208 + m0 + t;
    Wh1h[off] = s1;
    Wh2h[off] = s2;
  }

  // ---- direct Wh[b][f][96] stores (m-quads never straddle batches)
  #pragma unroll
  for (int mi = 0; mi < 2; ++mi) {
    unsigned mq = m0 + wm * 32 + mi * 16 + (l >> 4) * 4;
    unsigned bb = (unsigned)(((unsigned long long)mq * 46684428ull) >> 32);
    unsigned n2 = mq - bb * 92u;
    #pragma unroll
    for (int ni = 0; ni < 4; ++ni) {
      int C = n0 + wc * 64 + ni * 16 + (l & 15);
      half4 h;
      h[0] = (_Float16)acc[mi][ni][0]; h[1] = (_Float16)acc[mi][ni][1];
      h[2] = (_Float16)acc[mi][ni][2]; h[3] = (_Float16)acc[mi][ni][3];
      *(half4*)(Wh + ((size_t)bb * FOUT + C) * 96 + n2) = h;
    }
  }
}

// ---------------------------------------------------------------------------
// K2: per-batch attention (structure unchanged); Wh1/Wh2 = h0 + h1 partials.
// ---------------------------------------------------------------------------
__global__ __launch_bounds__(512, 4) void attn_kernel(
    const _Float16* __restrict__ Wh, const _Float16* __restrict__ ATp,
    const int* __restrict__ adj, const float* __restrict__ Wh1h,
    const float* __restrict__ Wh2h, const float* __restrict__ bias,
    float* __restrict__ out) {
  extern __shared__ char smem[];
  _Float16* at_  = (_Float16*)smem;                 // [96][104] 19968 B
  _Float16* e0a  = (_Float16*)(smem + 19968);       // [96][104] 19968 B
  _Float16* whc0 = (_Float16*)(smem + 39936);       // [64][104] 13312 B
  _Float16* whc1 = (_Float16*)(smem + 53248);       // [64][104] 13312 B
  float* w1s = (float*)(smem + 66560);              // [96]
  float* w2s = (float*)(smem + 66944);              // [96]

  int t = threadIdx.x, l = t & 63, w = t >> 6;
  int b = blockIdx.x;
  const _Float16* WhB = Wh + (size_t)b * FOUT * 96;

  half8 st[3][2];
  bool stager = (t < 384);
  int srow = t / 6, scol = (t - srow * 6) * 16;

#define K2_LD(S, C) do { if (stager) {                                         \
    st[S][0] = *(const half8*)(WhB + (C) * 6144 + t * 16);                     \
    st[S][1] = *(const half8*)(WhB + (C) * 6144 + t * 16 + 8); } } while (0)
#define K2_WR(BUF, S) do { if (stager) {                                       \
    *(half8*)((BUF) + srow * 104 + scol)     = st[S][0];                       \
    *(half8*)((BUF) + srow * 104 + scol + 8) = st[S][1]; } } while (0)

  K2_LD(0, 0);
  K2_LD(1, 1);

  for (int idx = t; idx < 1248; idx += 512)
    *(half8*)(at_ + idx * 8) = *(const half8*)(ATp + idx * 8);
  if (t < 96) {
    size_t m = (size_t)b * NNODE + t;
    w1s[t] = (t < 92) ? (Wh1h[m] + Wh1h[94208 + m]) : 0.f;
  } else if (t < 192) {
    int j = t - 96;
    size_t m = (size_t)b * NNODE + j;
    w2s[j] = (j < 92) ? (Wh2h[m] + Wh2h[94208 + m]) : 0.f;
  }
  BAR_LGKM();

  for (int idx = t; idx < 96 * 128; idx += 512) {
    int i = idx >> 7, k = idx & 127;
    if (k < 104) {
      float v = (i < 92 && k < 92) ? lrelu(w1s[i] + w2s[k]) : 0.f;
      e0a[i * 104 + k] = (_Float16)v;
    }
  }
  BAR_LGKM();

  if (w < 6) {
    f32x4 ez = {0.f, 0.f, 0.f, 0.f};
    f32x4 eacc[6];
    #pragma unroll
    for (int ni = 0; ni < 6; ++ni) eacc[ni] = ez;
    #pragma unroll
    for (int ks = 0; ks < 3; ++ks) {
      half8 ea = *(const half8*)((const char*)e0a +
                 (16 * w + (l & 15)) * 208 + ks * 64 + (l >> 4) * 16);
      #pragma unroll
      for (int ni = 0; ni < 6; ++ni) {
        half8 bt = *(const half8*)((const char*)at_ +
                   (16 * ni + (l & 15)) * 208 + ks * 64 + (l >> 4) * 16);
        eacc[ni] = __builtin_amdgcn_mfma_f32_16x16x32_f16(ea, bt, eacc[ni], 0, 0, 0);
      }
    }
    float attv[4][6];
    #pragma unroll
    for (int r = 0; r < 4; ++r) {
      int i = 16 * w + (l >> 4) * 4 + r;
      float s[6]; float m = -3.0e38f;
      #pragma unroll
      for (int ni = 0; ni < 6; ++ni) {
        int j = ni * 16 + (l & 15);
        float e = lrelu(eacc[ni][r]);
        float sv = -3.0e38f;
        if (i < 92 && j < 92) {
          int avj = adj[((size_t)b * NNODE + i) * NNODE + j];
          sv = (avj > 0) ? e : -9.0e15f;
        }
        s[ni] = sv;
        m = fmaxf(m, sv);
      }
      #pragma unroll
      for (int mm = 1; mm < 16; mm <<= 1) m = fmaxf(m, __shfl_xor(m, mm));
      float sum = 0.f; float p[6];
      #pragma unroll
      for (int ni = 0; ni < 6; ++ni) {
        int j = ni * 16 + (l & 15);
        p[ni] = (i < 92 && j < 92) ? __expf(s[ni] - m) : 0.f;
        sum += p[ni];
      }
      #pragma unroll
      for (int mm = 1; mm < 16; mm <<= 1) sum += __shfl_xor(sum, mm);
      float rs = (i < 92) ? (1.0f / sum) : 0.f;
      #pragma unroll
      for (int ni = 0; ni < 6; ++ni) attv[r][ni] = p[ni] * rs;
    }
    #pragma unroll
    for (int r = 0; r < 4; ++r) {
      int i = 16 * w + (l >> 4) * 4 + r;
      #pragma unroll
      for (int ni = 0; ni < 6; ++ni)
        e0a[i * 104 + ni * 16 + (l & 15)] = (_Float16)attv[r][ni];
    }
  }
  BAR_LGKM();

  K2_WR(whc0, 0);
  BAR_LGKM();

  int ih = w >> 2, fq = w & 3;
  #pragma unroll
  for (int c = 0; c < 8; ++c) {
    _Float16* cur = (c & 1) ? whc1 : whc0;
    _Float16* nxt = (c & 1) ? whc0 : whc1;
    if (c + 1 < 8) K2_WR(nxt, (c + 1) % 3);
    if (c + 2 < 8) K2_LD((c + 2) % 3, c + 2);
    f32x4 pz = {0.f, 0.f, 0.f, 0.f};
    f32x4 pacc[3];
    pacc[0] = pz; pacc[1] = pz; pacc[2] = pz;
    #pragma unroll
    for (int ks = 0; ks < 3; ++ks) {
      half8 bf = *(const half8*)((const char*)cur +
                 (fq * 16 + (l & 15)) * 208 + ks * 64 + (l >> 4) * 16);
      #pragma unroll
      for (int q = 0; q < 3; ++q) {
        half8 af = *(const half8*)((const char*)e0a +
                   (16 * (ih * 3 + q) + (l & 15)) * 208 + ks * 64 + (l >> 4) * 16);
        pacc[q] = __builtin_amdgcn_mfma_f32_16x16x32_f16(af, bf, pacc[q], 0, 0, 0);
      }
    }
    int fcol = c * 64 + fq * 16 + (l & 15);
    float bv = bias[fcol];
    #pragma unroll
    for (int q = 0; q < 3; ++q)
      #pragma unroll
      for (int r = 0; r < 4; ++r) {
        int i = 16 * (ih * 3 + q) + (l >> 4) * 4 + r;
        if (i < 92)
          out[((size_t)b * NNODE + i) * FOUT + fcol] = pacc[q][r] + bv;
      }
    if (c + 1 < 8) BAR_LGKM();
  }
}

// ---------------------------------------------------------------------------
extern "C" void kernel_launch(void* const* d_in, const int* in_sizes, int n_in,
                              void* d_out, int out_size, void* d_ws, size_t ws_size,
                              hipStream_t stream) {
  (void)in_sizes; (void)n_in; (void)out_size; (void)ws_size;
  const float* X    = (const float*)d_in[0];
  const int*   adj  = (const int*)d_in[1];
  const float* W    = (const float*)d_in[2];
  const float* av   = (const float*)d_in[3];
  const float* Am   = (const float*)d_in[4];
  const float* bias = (const float*)d_in[5];
  float* out = (float*)d_out;
  char* ws = (char*)d_ws;

  _Float16* WT  = (_Float16*)(ws);              // 1,048,576 B
  _Float16* ATp = (_Float16*)(ws + 1048576);    //    19,968 B
  float* Wh1h = (float*)(ws + 1068544);         // 2 x 376,832 B
  float* Wh2h = (float*)(ws + 1822208);         // 2 x 376,832 B
  _Float16* Wh = (_Float16*)(ws + 2575872);     // 100,663,296 B  [b][f][96]

  prep_kernel<<<68, 256, 0, stream>>>(W, Am, WT, ATp);
  hipFuncSetAttribute((const void*)gemm_kernel,
                      hipFuncAttributeMaxDynamicSharedMemorySize, 43008);
  gemm_kernel<<<2944, 512, 43008, stream>>>(X, WT, av, Wh, Wh1h, Wh2h);
  hipFuncSetAttribute((const void*)attn_kernel,
                      hipFuncAttributeMaxDynamicSharedMemorySize, 67584);
  attn_kernel<<<1024, 512, 67584, stream>>>(Wh, ATp, adj, Wh1h, Wh2h, bias, out);
}